// Round 16
// baseline (738.633 us; speedup 1.0000x reference)
//
#include <hip/hip_runtime.h>
#include <hip/hip_bf16.h>
#include <math.h>

#define B_   16
#define S_   1024
#define D_   256
#define H_   8
#define HD_  32
#define L_   6
#define H2_  1024
#define LN_EPS 1e-5f
#define LOG2E_ 1.4426950408889634f
#define SCALE_ 0.17677669529663687f  // 1/sqrt(32)

typedef __attribute__((ext_vector_type(8))) short frag;    // 8 bf16 (4 VGPRs)
typedef __attribute__((ext_vector_type(4))) float f32x4;

#define MFMA(a, b, c) __builtin_amdgcn_mfma_f32_16x16x32_bf16((a), (b), (c), 0, 0, 0)

__device__ inline ushort bf16b(float f) {
    uint u = __builtin_bit_cast(uint, f);
    u += 0x7fff + ((u >> 16) & 1);       // RNE
    return (ushort)(u >> 16);
}
__device__ inline uint cvt_pk_bf16(float lo, float hi) {
    uint r;
    asm("v_cvt_pk_bf16_f32 %0, %1, %2" : "=v"(r) : "v"(lo), "v"(hi));
    return r;
}
__device__ inline float exp2_raw(float x) {   // raw v_exp_f32 (2^x)
    float r;
    asm("v_exp_f32 %0, %1" : "=v"(r) : "v"(x));
    return r;
}
// async global->LDS, 16B per lane (dest = wave-uniform base + lane*16)
__device__ __forceinline__ void gload16(const ushort* g, ushort* l) {
    __builtin_amdgcn_global_load_lds(
        (const __attribute__((address_space(1))) uint*)g,
        (__attribute__((address_space(3))) uint*)l, 16, 0, 0);
}

// ---------------------------------------------------------------------------
// Weight transpose + f32->bf16: in [K][N] f32 -> out [N][K] bf16 (per layer z)
// ---------------------------------------------------------------------------
__global__ __launch_bounds__(256) void wtr_kernel(
    const float* __restrict__ in, ushort* __restrict__ out, int K, int N)
{
    __shared__ ushort Ts[32][36];
    in  += (size_t)blockIdx.z * K * N;
    out += (size_t)blockIdx.z * K * N;
    int n0 = blockIdx.x * 32, k0 = blockIdx.y * 32;
    int r = threadIdx.x >> 3, c4 = (threadIdx.x & 7) * 4;
    float4 f = *(const float4*)(in + (size_t)(k0 + r) * N + n0 + c4);
    Ts[r][c4 + 0] = bf16b(f.x);
    Ts[r][c4 + 1] = bf16b(f.y);
    Ts[r][c4 + 2] = bf16b(f.z);
    Ts[r][c4 + 3] = bf16b(f.w);
    __syncthreads();
    ushort4 o = { Ts[c4 + 0][r], Ts[c4 + 1][r], Ts[c4 + 2][r], Ts[c4 + 3][r] };
    *(ushort4*)(out + (size_t)(n0 + r) * K + k0 + c4) = o;
}

// ---------------------------------------------------------------------------
// Embedding (f32 out)
// ---------------------------------------------------------------------------
__global__ __launch_bounds__(256) void embed_kernel(
    const int* __restrict__ tokens, const int* __restrict__ pos_ids,
    const float* __restrict__ emb, const float* __restrict__ iwp,
    const float* __restrict__ pwp, float* __restrict__ X)
{
    int bs = blockIdx.x;
    int s = bs & (S_ - 1);
    int d = threadIdx.x;
    int tok = tokens[bs];
    float p = (float)pos_ids[s];
    int j = (d < 128) ? d : (d - 128);
    float invf = exp2f(-(float)j * (13.287712379549449f / 128.0f));
    float ang = p * invf;
    float pe = (d < 128) ? sinf(ang) : cosf(ang);
    X[(size_t)bs * D_ + d] = iwp[0] * emb[tok * D_ + d] + pwp[0] * pe;
}

// ---------------------------------------------------------------------------
// LayerNorm (standalone): MODE 0: f32 row-major out. MODE 2: bf16 row-major.
// ---------------------------------------------------------------------------
template<int MODE>
__global__ __launch_bounds__(256) void ln_kernel(
    const float* __restrict__ X, const float* __restrict__ w,
    const float* __restrict__ b, void* __restrict__ outp)
{
    int row = blockIdx.x * 4 + (threadIdx.x >> 6);
    int lane = threadIdx.x & 63;
    const float4 v = *(const float4*)(X + (size_t)row * D_ + lane * 4);
    float s = v.x + v.y + v.z + v.w;
    #pragma unroll
    for (int m = 1; m < 64; m <<= 1) s += __shfl_xor(s, m, 64);
    float mu = s * (1.0f / 256.0f);
    float dx = v.x - mu, dy = v.y - mu, dz = v.z - mu, dw = v.w - mu;
    float vs = dx * dx + dy * dy + dz * dz + dw * dw;
    #pragma unroll
    for (int m = 1; m < 64; m <<= 1) vs += __shfl_xor(vs, m, 64);
    float inv = rsqrtf(vs * (1.0f / 256.0f) + LN_EPS);
    float4 wv = *(const float4*)(w + lane * 4);
    float4 bv = *(const float4*)(b + lane * 4);
    float o0 = dx * inv * wv.x + bv.x;
    float o1 = dy * inv * wv.y + bv.y;
    float o2 = dz * inv * wv.z + bv.z;
    float o3 = dw * inv * wv.w + bv.w;
    if constexpr (MODE == 0) {
        float4 o = { o0, o1, o2, o3 };
        *(float4*)((float*)outp + (size_t)row * D_ + lane * 4) = o;
    } else {
        ushort4 o = { bf16b(o0), bf16b(o1), bf16b(o2), bf16b(o3) };
        *(ushort4*)((ushort*)outp + (size_t)row * D_ + lane * 4) = o;
    }
}

// ---------------------------------------------------------------------------
// Fused LN + head-pack + V-transpose (as R11).
// ---------------------------------------------------------------------------
__global__ __launch_bounds__(256) void lnv_kernel(
    const float* __restrict__ X, const float* __restrict__ w,
    const float* __restrict__ b, ushort* __restrict__ XNB,
    ushort* __restrict__ VTI)
{
    __shared__ ushort Ts[64][264];
    const int blk = blockIdx.x;
    const int bb = blk >> 4;                 // batch
    const int sblk = (blk & 15) * 64;        // s-block base
    const int wv = threadIdx.x >> 6, lane = threadIdx.x & 63;

    #pragma unroll
    for (int p = 0; p < 16; ++p) {
        int srow = p * 4 + wv;               // 0..63
        int row = bb * S_ + sblk + srow;
        const float4 v = *(const float4*)(X + (size_t)row * D_ + lane * 4);
        float s = v.x + v.y + v.z + v.w;
        #pragma unroll
        for (int m = 1; m < 64; m <<= 1) s += __shfl_xor(s, m, 64);
        float mu = s * (1.0f / 256.0f);
        float dx = v.x - mu, dy = v.y - mu, dz = v.z - mu, dw = v.w - mu;
        float vs = dx * dx + dy * dy + dz * dz + dw * dw;
        #pragma unroll
        for (int m = 1; m < 64; m <<= 1) vs += __shfl_xor(vs, m, 64);
        float inv = rsqrtf(vs * (1.0f / 256.0f) + LN_EPS);
        float4 wvv = *(const float4*)(w + lane * 4);
        float4 bvv = *(const float4*)(b + lane * 4);
        ushort4 o = { bf16b(dx * inv * wvv.x + bvv.x),
                      bf16b(dy * inv * wvv.y + bvv.y),
                      bf16b(dz * inv * wvv.z + bvv.z),
                      bf16b(dw * inv * wvv.w + bvv.w) };
        int h = lane >> 3, dd = (lane & 7) * 4;
        *(ushort4*)(XNB + (((size_t)(bb * H_ + h) * S_ + sblk + srow) * HD_ + dd)) = o;
        *(ushort4*)&Ts[srow][lane * 4] = o;
    }
    __syncthreads();

    const int h = threadIdx.x >> 5, d = threadIdx.x & 31;
    const int hd = threadIdx.x;              // column in Ts
    ushort* dst = VTI + ((size_t)(bb * H_ + h) * HD_ + d) * S_ + sblk;
    #pragma unroll
    for (int c8 = 0; c8 < 8; ++c8) {
        uint4 o;
        uint tmp[4];
        #pragma unroll
        for (int pair = 0; pair < 4; ++pair) {
            int c0 = c8 * 8 + pair * 2;
            int c1 = c0 + 1;
            int t0 = 16 * (((c0 >> 5) & 1) + 2 * ((c0 >> 2) & 1)) + 4 * ((c0 >> 3) & 3) + (c0 & 3);
            int t1 = 16 * (((c1 >> 5) & 1) + 2 * ((c1 >> 2) & 1)) + 4 * ((c1 >> 3) & 3) + (c1 & 3);
            tmp[pair] = (uint)Ts[t0][hd] | ((uint)Ts[t1][hd] << 16);
        }
        o.x = tmp[0]; o.y = tmp[1]; o.z = tmp[2]; o.w = tmp[3];
        *(uint4*)(dst + c8 * 8) = o;
    }
}

// ---------------------------------------------------------------------------
// Flash attention v7 (R15: 128-key rounds, cheap EXACTR). Unchanged.
// ---------------------------------------------------------------------------
__global__ __launch_bounds__(256) void attn_kernel(
    const ushort* __restrict__ XNB, const ushort* __restrict__ VTI,
    float* __restrict__ X)
{
    __shared__ ushort Kl[2][4096];
    __shared__ ushort Vl[2][4096];

    const int bi = blockIdx.x;
    const int xcd = bi & 7, m = bi >> 3;          // m in [0,128)
    const int bh = xcd * 16 + (m >> 3);           // 16 bh per XCD
    const int bx = m & 7;                         // q-block (of 128) within bh
    const int b = bh >> 3, h = bh & 7;

    const ushort* __restrict__ base = XNB + (size_t)bh * (S_ * HD_);
    const ushort* __restrict__ vbase = VTI + (size_t)bh * (HD_ * S_);
    const int tid = threadIdx.x;
    const int w = tid >> 6, l = tid & 63, g = l >> 4, ll = l & 15;
    const int q0 = bx * 128 + w * 32;
    const int qgA = q0 + ll, qgB = q0 + 16 + ll;
    const int xq = q0 >> 5;
    const float C1 = SCALE_ * LOG2E_;

    frag qfA = *(const frag*)(base + (size_t)qgA * HD_ + g * 8);
    frag qfB = *(const frag*)(base + (size_t)qgB * HD_ + g * 8);
    #pragma unroll
    for (int i = 0; i < 8; ++i) {
        float fa = __builtin_bit_cast(float, ((uint)(ushort)qfA[i]) << 16);
        float fb = __builtin_bit_cast(float, ((uint)(ushort)qfB[i]) << 16);
        qfA[i] = (short)bf16b(fa * C1);
        qfB[i] = (short)bf16b(fb * C1);
    }

    const float slr = -exp2f(-(0.5f + (float)h)) * LOG2E_;
    const float sll = -exp2f(-(1.0f + (float)h)) * LOG2E_;
    const int itb = 2 * bx + (w >> 1);

    float dabs[4], d16m[4], d16p[4];
    #pragma unroll
    for (int r = 0; r < 4; ++r) {
        int del = ll - 4 * g - r;
        dabs[r] = (float)abs(del);
        d16m[r] = (float)(16 - del);
        d16p[r] = (float)(16 + del);
    }

    f32x4 o0A = {0,0,0,0}, o1A = {0,0,0,0}, osA = {0,0,0,0};
    f32x4 o0B = {0,0,0,0}, o1B = {0,0,0,0}, osB = {0,0,0,0};
    const f32x4 zc = {0,0,0,0};
    const short one_s = (short)0x3F80;
    const frag ones = { one_s, one_s, one_s, one_s, one_s, one_s, one_s, one_s };

    const ushort* ksrc = base  + (size_t)(16 * w + ll) * HD_ + g * 8;
    const ushort* vsrc = vbase + (size_t)((w >> 1) * 16 + ll) * S_ + (w & 1) * 32 + g * 8;
    const int dst = (w * 64 + l) * 8;

#define STAGE(NB, T2)                                                         \
    gload16(ksrc + (size_t)(T2) * 128 * HD_,            &Kl[NB][dst]);        \
    gload16(ksrc + (size_t)(T2) * 128 * HD_ + 64 * HD_, &Kl[NB][dst + 2048]); \
    gload16(vsrc + (T2) * 128,                          &Vl[NB][dst]);        \
    gload16(vsrc + (T2) * 128 + 64,                     &Vl[NB][dst + 2048]);

    STAGE(0, 0)
    __syncthreads();

#define EXACTR(r)                                                             \
  { int t0 = tb + 4 * g + (r);                                                \
    float sA0 = (t0      > qgA) ? slr : sll;                                  \
    float sA1 = (t0 + 16 > qgA) ? slr : sll;                                  \
    float sA2 = (t0 + 32 > qgA) ? slr : sll;                                  \
    float sA3 = (t0 + 48 > qgA) ? slr : sll;                                  \
    float sB0 = (t0      > qgB) ? slr : sll;                                  \
    float sB1 = (t0 + 16 > qgB) ? slr : sll;                                  \
    float sB2 = (t0 + 32 > qgB) ? slr : sll;                                  \
    float sB3 = (t0 + 48 > qgB) ? slr : sll;                                  \
    eA0[r] = exp2_raw(fmaf(sA0, dabs[r] + ax0, sa0[r]));                      \
    eA1[r] = exp2_raw(fmaf(sA1, d16m[r] + ax0, sa1[r]));                      \
    eA2[r] = exp2_raw(fmaf(sA2, dabs[r] + ax1, sa2[r]));                      \
    eA3[r] = exp2_raw(fmaf(sA3, d16m[r] + ax1, sa3[r]));                      \
    eB0[r] = exp2_raw(fmaf(sB0, d16p[r] + ax0, sb0[r]));                      \
    eB1[r] = exp2_raw(fmaf(sB1, dabs[r] + ax0, sb1[r]));                      \
    eB2[r] = exp2_raw(fmaf(sB2, d16p[r] + ax1, sb2[r]));                      \
    eB3[r] = exp2_raw(fmaf(sB3, dabs[r] + ax1, sb3[r])); }

#define FASTR(r)                                                              \
    eA0[r] = exp2_raw(fmaf(sl, dabs[r] + ax0, sa0[r]));                       \
    eA1[r] = exp2_raw(fmaf(sl, d16m[r] + ax0, sa1[r]));                       \
    eA2[r] = exp2_raw(fmaf(sl, dabs[r] + ax1, sa2[r]));                       \
    eA3[r] = exp2_raw(fmaf(sl, d16m[r] + ax1, sa3[r]));                       \
    eB0[r] = exp2_raw(fmaf(sl, d16p[r] + ax0, sb0[r]));                       \
    eB1[r] = exp2_raw(fmaf(sl, dabs[r] + ax0, sb1[r]));                       \
    eB2[r] = exp2_raw(fmaf(sl, d16p[r] + ax1, sb2[r]));                       \
    eB3[r] = exp2_raw(fmaf(sl, dabs[r] + ax1, sb3[r]));

#define HALF(IT, OFF)                                                         \
  { const int tb = (IT) * 64;                                                 \
    frag K0 = *(const frag*)&Kl[cur][(OFF) + l * 8];                          \
    frag K1 = *(const frag*)&Kl[cur][(OFF) + 512 + l * 8];                    \
    frag K2 = *(const frag*)&Kl[cur][(OFF) + 1024 + l * 8];                   \
    frag K3 = *(const frag*)&Kl[cur][(OFF) + 1536 + l * 8];                   \
    frag V0 = *(const frag*)&Vl[cur][(OFF) + l * 8];                          \
    frag V2 = *(const frag*)&Vl[cur][(OFF) + 512 + l * 8];                    \
    frag V1 = *(const frag*)&Vl[cur][(OFF) + 1024 + l * 8];                   \
    frag V3 = *(const frag*)&Vl[cur][(OFF) + 1536 + l * 8];                   \
    f32x4 sa0 = MFMA(K0, qfA, zc);                                            \
    f32x4 sa1 = MFMA(K1, qfA, zc);                                            \
    f32x4 sa2 = MFMA(K2, qfA, zc);                                            \
    f32x4 sa3 = MFMA(K3, qfA, zc);                                            \
    f32x4 sb0 = MFMA(K0, qfB, zc);                                            \
    f32x4 sb1 = MFMA(K1, qfB, zc);                                            \
    f32x4 sb2 = MFMA(K2, qfB, zc);                                            \
    f32x4 sb3 = MFMA(K3, qfB, zc);                                            \
    const float ax0 = (float)abs(xq - 2 * (IT));                              \
    const float ax1 = (float)abs(xq - 2 * (IT) - 1);                          \
    f32x4 eA0, eA1, eA2, eA3, eB0, eB1, eB2, eB3;                             \
    if ((IT) == itb) {                                                        \
        EXACTR(0) EXACTR(1) EXACTR(2) EXACTR(3)                               \
    } else {                                                                  \
        const float sl = ((IT) > itb) ? slr : sll;                            \
        FASTR(0) FASTR(1) FASTR(2) FASTR(3)                                   \
    }                                                                         \
    uint4 pa0 = { cvt_pk_bf16(eA0[0], eA0[1]), cvt_pk_bf16(eA0[2], eA0[3]),   \
                  cvt_pk_bf16(eA2[0], eA2[1]), cvt_pk_bf16(eA2[2], eA2[3]) }; \
    uint4 pa1 = { cvt_pk_bf16(eA1[0], eA1[1]), cvt_pk_bf16(eA1[2], eA1[3]),   \
                  cvt_pk_bf16(eA3[0], eA3[1]), cvt_pk_bf16(eA3[2], eA3[3]) }; \
    uint4 pb0 = { cvt_pk_bf16(eB0[0], eB0[1]), cvt_pk_bf16(eB0[2], eB0[3]),   \
                  cvt_pk_bf16(eB2[0], eB2[1]), cvt_pk_bf16(eB2[2], eB2[3]) }; \
    uint4 pb1 = { cvt_pk_bf16(eB1[0], eB1[1]), cvt_pk_bf16(eB1[2], eB1[3]),   \
                  cvt_pk_bf16(eB3[0], eB3[1]), cvt_pk_bf16(eB3[2], eB3[3]) }; \
    frag pfA0 = __builtin_bit_cast(frag, pa0);                                \
    frag pfA1 = __builtin_bit_cast(frag, pa1);                                \
    frag pfB0 = __builtin_bit_cast(frag, pb0);                                \
    frag pfB1 = __builtin_bit_cast(frag, pb1);                                \
    o0A = MFMA(pfA0, V0, o0A);  o1A = MFMA(pfA0, V1, o1A);                    \
    osA = MFMA(pfA0, ones, osA);                                              \
    o0A = MFMA(pfA1, V2, o0A);  o1A = MFMA(pfA1, V3, o1A);                    \
    osA = MFMA(pfA1, ones, osA);                                              \
    o0B = MFMA(pfB0, V0, o0B);  o1B = MFMA(pfB0, V1, o1B);                    \
    osB = MFMA(pfB0, ones, osB);                                              \
    o0B = MFMA(pfB1, V2, o0B);  o1B = MFMA(pfB1, V3, o1B);                    \
    osB = MFMA(pfB1, ones, osB); }

    for (int rt = 0; rt < 8; ++rt) {
        const int cur = rt & 1, nxt = cur ^ 1;
        STAGE(nxt, (rt + 1) & 7)
        HALF(2 * rt, 0)
        HALF(2 * rt + 1, 2048)
        __syncthreads();
    }
#undef HALF
#undef FASTR
#undef EXACTR
#undef STAGE

    #pragma unroll
    for (int r = 0; r < 4; ++r) {
        float invA = 1.0f / osA[r];
        float invB = 1.0f / osB[r];
        float* xpA = X + ((size_t)(b * S_ + q0 + g * 4 + r)) * D_ + h * HD_;
        float* xpB = X + ((size_t)(b * S_ + q0 + 16 + g * 4 + r)) * D_ + h * HD_;
        xpA[ll]      += o0A[r] * invA;
        xpA[16 + ll] += o1A[r] * invA;
        xpB[ll]      += o0B[r] * invB;
        xpB[16 + ll] += o1B[r] * invB;
    }
}

// ---------------------------------------------------------------------------
// GEMM1 (row-chunked): H[rows roff..roff+NRT*128) = GELU(A @ W1^T + b1).
// BK=64. grid = NRT*8 blocks (8 col-tiles per row-tile), XCD-contiguous:
// XCD x covers row-tiles [x*NRT/8, (x+1)*NRT/8) of the chunk.
// ---------------------------------------------------------------------------
__global__ __launch_bounds__(256) void gemm1_kernel(
    const ushort* __restrict__ A, const ushort* __restrict__ Bt,
    const float* __restrict__ bias, ushort* __restrict__ Hout,
    int roff, int rtiles_per_xcd)
{
    __shared__ ushort As[2 * 4096];
    __shared__ ushort Bs[2 * 4096];
    const int bid = blockIdx.x;
    const int xcd = bid & 7, i = bid >> 3;
    const int row0 = roff + (xcd * rtiles_per_xcd + (i >> 3)) * 128;
    const int col0 = (i & 7) * 128;
    const int tid = threadIdx.x;
    const int w = tid >> 6, l = tid & 63, g = l >> 4, ll = l & 15;
    const int wm = w >> 1, wn = w & 1;

    const int srow = w * 32 + (l >> 2);
    const int scol = (l & 3) * 8;
    const ushort* ga = A  + (size_t)(row0 + srow) * 256 + scol;
    const ushort* gb = Bt + (size_t)(col0 + srow) * 256 + scol;
    const int dst = w * 1024 + l * 8;

    f32x4 acc[4][4] = {};
    for (int k0 = 0; k0 < 256; k0 += 64) {
        __syncthreads();
        #pragma unroll
        for (int sub = 0; sub < 2; ++sub) {
            gload16(ga + k0 + sub * 32,            &As[sub * 4096 + dst]);
            gload16(ga + k0 + sub * 32 + 16 * 256, &As[sub * 4096 + dst + 512]);
            gload16(gb + k0 + sub * 32,            &Bs[sub * 4096 + dst]);
            gload16(gb + k0 + sub * 32 + 16 * 256, &Bs[sub * 4096 + dst + 512]);
        }
        __syncthreads();
        #pragma unroll
        for (int sub = 0; sub < 2; ++sub) {
            frag af[4], bfr[4];
            #pragma unroll
            for (int mb = 0; mb < 4; ++mb)
                af[mb] = *(const frag*)&As[sub * 4096 + (wm * 64 + mb * 16 + ll) * 32 + g * 8];
            #pragma unroll
            for (int nb = 0; nb < 4; ++nb)
                bfr[nb] = *(const frag*)&Bs[sub * 4096 + (wn * 64 + nb * 16 + ll) * 32 + g * 8];
            #pragma unroll
            for (int mb = 0; mb < 4; ++mb)
                #pragma unroll
                for (int nb = 0; nb < 4; ++nb)
                    acc[mb][nb] = MFMA(af[mb], bfr[nb], acc[mb][nb]);
        }
    }

    #pragma unroll
    for (int nb = 0; nb < 4; ++nb) {
        int col = col0 + wn * 64 + nb * 16 + ll;
        float bv = bias[col];
        #pragma unroll
        for (int mb = 0; mb < 4; ++mb) {
            #pragma unroll
            for (int r = 0; r < 4; ++r) {
                int row = row0 + wm * 64 + mb * 16 + g * 4 + r;
                float v = acc[mb][nb][r] + bv;
                float u2 = 1.5957691216f * v + 0.0713548162f * (v * v * v);
                float e = exp2_raw(u2 * LOG2E_);
                float rr = __builtin_amdgcn_rcpf(e + 1.0f);
                float gl = v - v * rr;
                Hout[(size_t)row * 1024 + col] = bf16b(gl);
            }
        }
    }
}

// ---------------------------------------------------------------------------
// GEMM2 (row-chunked): X[rows roff..) += A @ W2^T + b2. BK=64.
// grid = NRT*4 blocks (4 col-tiles of 64). XCD-contiguous rows match gemm1's
// chunk mapping so the chunk's hbuf slice is L2-resident across the pair.
// ---------------------------------------------------------------------------
__global__ __launch_bounds__(256) void gemm2_kernel(
    const ushort* __restrict__ A, const ushort* __restrict__ Bt,
    const float* __restrict__ bias, float* __restrict__ X,
    int roff, int rtiles_per_xcd)
{
    __shared__ ushort As[2 * 4096];
    __shared__ ushort Bs[2 * 2048];
    const int bid = blockIdx.x;
    const int xcd = bid & 7, i = bid >> 3;
    const int row0 = roff + (xcd * rtiles_per_xcd + (i >> 2)) * 128;
    const int col0 = (i & 3) * 64;
    const int tid = threadIdx.x;
    const int w = tid >> 6, l = tid & 63, g = l >> 4, ll = l & 15;

    const int srow = w * 32 + (l >> 2);
    const int scol = (l & 3) * 8;
    const ushort* ga = A  + (size_t)(row0 + srow) * 1024 + scol;
    const ushort* gb = Bt + (size_t)(col0 + w * 16 + (l >> 2)) * 1024 + scol;
    const int dstA = w * 1024 + l * 8;
    const int dstB = w * 512 + l * 8;

    f32x4 acc[2][4] = {};
    for (int k0 = 0; k0 < 1024; k0 += 64) {
        __syncthreads();
        #pragma unroll
        for (int sub = 0; sub < 2; ++sub) {
            gload16(ga + k0 + sub * 32,             &As[sub * 4096 + dstA]);
            gload16(ga + k0 + sub * 32 + 16 * 1024, &As[sub * 4096 + dstA + 512]);
            gload16(gb + k0 + sub * 32,             &Bs[sub * 2048 + dstB]);
        }
        __syncthreads();
        #pragma unroll
        for (int sub = 0; sub < 2; ++sub) {
            frag af[2], bfr[4];
            #pragma unroll
            for (int mb = 0; mb < 2; ++mb)
                af[mb] = *(const frag*)&As[sub * 4096 + (w * 32 + mb * 16 + ll) * 32 + g * 8];
            #pragma unroll
            for (int nb = 0; nb < 4; ++nb)
                bfr[nb] = *(const frag*)&Bs[sub * 2048 + (nb * 16 + ll) * 32 + g * 8];
            #pragma unroll
            for (int mb = 0; mb < 2; ++mb)
                #pragma unroll
                for (int nb = 0; nb < 4; ++nb)
                    acc[mb][nb] = MFMA(af[mb], bfr[nb], acc[mb][nb]);
        }
    }

    #pragma unroll
    for (int nb = 0; nb < 4; ++nb) {
        int col = col0 + nb * 16 + ll;
        float bv = bias[col];
        #pragma unroll
        for (int mb = 0; mb < 2; ++mb) {
            #pragma unroll
            for (int r = 0; r < 4; ++r) {
                int row = row0 + w * 32 + mb * 16 + g * 4 + r;
                float* xp = X + (size_t)row * 256 + col;
                *xp += acc[mb][nb][r] + bv;
            }
        }
    }
}

// ---------------------------------------------------------------------------
extern "C" void kernel_launch(void* const* d_in, const int* in_sizes, int n_in,
                              void* d_out, int out_size, void* d_ws, size_t ws_size,
                              hipStream_t stream)
{
    const int*   tokens  = (const int*)d_in[0];
    const int*   pos_ids = (const int*)d_in[1];
    const float* emb     = (const float*)d_in[2];
    const float* iw      = (const float*)d_in[3];
    const float* pw      = (const float*)d_in[4];
    const float* ln1w    = (const float*)d_in[5];
    const float* ln1b    = (const float*)d_in[6];
    const float* ln2w    = (const float*)d_in[7];
    const float* ln2b    = (const float*)d_in[8];
    const float* w1      = (const float*)d_in[9];
    const float* b1      = (const float*)d_in[10];
    const float* w2      = (const float*)d_in[11];
    const float* b2      = (const float*)d_in[12];
    const float* lnfw    = (const float*)d_in[13];
    const float* lnfb    = (const float*)d_in[14];

    float* x = (float*)d_out;                    // [B,S,D] f32 residual stream
    char* ws = (char*)d_ws;
    ushort* xn   = (ushort*)ws;                  // 8,388,608 B
    ushort* vti  = (ushort*)(ws + 8388608);      // 8,388,608 B
    ushort* hbuf = (ushort*)(ws + 16777216);     // 33,554,432 B
    ushort* w1t  = (ushort*)(ws + 50331648);     // 3,145,728 B  [L][1024][256]
    ushort* w2t  = (ushort*)(ws + 53477376);     // 3,145,728 B  [L][256][1024]

    wtr_kernel<<<dim3(32, 8, L_), 256, 0, stream>>>(w1, w1t, 256, 1024);
    wtr_kernel<<<dim3(8, 32, L_), 256, 0, stream>>>(w2, w2t, 1024, 256);

    embed_kernel<<<B_ * S_, 256, 0, stream>>>(tokens, pos_ids, emb, iw, pw, x);

    // MLP row-chunking: 2 chunks of 8192 rows (64 row-tiles; 8 per XCD ->
    // 2.1 MB hbuf slice per XCD L2, resident across the gemm1->gemm2 pair).
    const int NCH = 2;
    const int RT_PER_CHUNK = 128 / NCH;          // 64 row-tiles per chunk
    const int RT_PER_XCD = RT_PER_CHUNK / 8;     // 8

    for (int l = 0; l < L_; l++) {
        lnv_kernel<<<(B_ * S_) / 64, 256, 0, stream>>>(
            x, ln1w + l * D_, ln1b + l * D_, xn, vti);
        attn_kernel<<<(S_ / 128) * B_ * H_, 256, 0, stream>>>(xn, vti, x);
        ln_kernel<2><<<(B_ * S_) / 4, 256, 0, stream>>>(x, ln2w + l * D_, ln2b + l * D_, xn);
        for (int c = 0; c < NCH; ++c) {
            const int roff = c * RT_PER_CHUNK * 128;
            gemm1_kernel<<<RT_PER_CHUNK * 8, 256, 0, stream>>>(
                xn, w1t + (size_t)l * D_ * H2_, b1 + (size_t)l * H2_, hbuf,
                roff, RT_PER_XCD);
            gemm2_kernel<<<RT_PER_CHUNK * 4, 256, 0, stream>>>(
                hbuf, w2t + (size_t)l * H2_ * D_, b2 + (size_t)l * D_, x,
                roff, RT_PER_XCD);
        }
    }
    ln_kernel<0><<<(B_ * S_) / 4, 256, 0, stream>>>(x, lnfw, lnfb, x);
}

// Round 17
// 639.510 us; speedup vs baseline: 1.1550x; 1.1550x over previous
//
#include <hip/hip_runtime.h>
#include <hip/hip_bf16.h>
#include <math.h>

#define B_   16
#define S_   1024
#define D_   256
#define H_   8
#define HD_  32
#define L_   6
#define H2_  1024
#define LN_EPS 1e-5f
#define LOG2E_ 1.4426950408889634f
#define SCALE_ 0.17677669529663687f  // 1/sqrt(32)

typedef __attribute__((ext_vector_type(8))) short frag;    // 8 bf16 (4 VGPRs)
typedef __attribute__((ext_vector_type(4))) float f32x4;

#define MFMA(a, b, c) __builtin_amdgcn_mfma_f32_16x16x32_bf16((a), (b), (c), 0, 0, 0)

__device__ inline ushort bf16b(float f) {
    uint u = __builtin_bit_cast(uint, f);
    u += 0x7fff + ((u >> 16) & 1);       // RNE
    return (ushort)(u >> 16);
}
__device__ inline uint cvt_pk_bf16(float lo, float hi) {
    uint r;
    asm("v_cvt_pk_bf16_f32 %0, %1, %2" : "=v"(r) : "v"(lo), "v"(hi));
    return r;
}
__device__ inline float exp2_raw(float x) {   // raw v_exp_f32 (2^x)
    float r;
    asm("v_exp_f32 %0, %1" : "=v"(r) : "v"(x));
    return r;
}
// async global->LDS, 16B per lane (dest = wave-uniform base + lane*16)
__device__ __forceinline__ void gload16(const ushort* g, ushort* l) {
    __builtin_amdgcn_global_load_lds(
        (const __attribute__((address_space(1))) uint*)g,
        (__attribute__((address_space(3))) uint*)l, 16, 0, 0);
}

// ---------------------------------------------------------------------------
// Weight transpose + f32->bf16: in [K][N] f32 -> out [N][K] bf16 (per layer z)
// ---------------------------------------------------------------------------
__global__ __launch_bounds__(256) void wtr_kernel(
    const float* __restrict__ in, ushort* __restrict__ out, int K, int N)
{
    __shared__ ushort Ts[32][36];
    in  += (size_t)blockIdx.z * K * N;
    out += (size_t)blockIdx.z * K * N;
    int n0 = blockIdx.x * 32, k0 = blockIdx.y * 32;
    int r = threadIdx.x >> 3, c4 = (threadIdx.x & 7) * 4;
    float4 f = *(const float4*)(in + (size_t)(k0 + r) * N + n0 + c4);
    Ts[r][c4 + 0] = bf16b(f.x);
    Ts[r][c4 + 1] = bf16b(f.y);
    Ts[r][c4 + 2] = bf16b(f.z);
    Ts[r][c4 + 3] = bf16b(f.w);
    __syncthreads();
    ushort4 o = { Ts[c4 + 0][r], Ts[c4 + 1][r], Ts[c4 + 2][r], Ts[c4 + 3][r] };
    *(ushort4*)(out + (size_t)(n0 + r) * K + k0 + c4) = o;
}

// ---------------------------------------------------------------------------
// Embedding (f32 out)
// ---------------------------------------------------------------------------
__global__ __launch_bounds__(256) void embed_kernel(
    const int* __restrict__ tokens, const int* __restrict__ pos_ids,
    const float* __restrict__ emb, const float* __restrict__ iwp,
    const float* __restrict__ pwp, float* __restrict__ X)
{
    int bs = blockIdx.x;
    int s = bs & (S_ - 1);
    int d = threadIdx.x;
    int tok = tokens[bs];
    float p = (float)pos_ids[s];
    int j = (d < 128) ? d : (d - 128);
    float invf = exp2f(-(float)j * (13.287712379549449f / 128.0f));
    float ang = p * invf;
    float pe = (d < 128) ? sinf(ang) : cosf(ang);
    X[(size_t)bs * D_ + d] = iwp[0] * emb[tok * D_ + d] + pwp[0] * pe;
}

// ---------------------------------------------------------------------------
// LayerNorm (standalone): MODE 0: f32 row-major out. MODE 2: bf16 row-major.
// ---------------------------------------------------------------------------
template<int MODE>
__global__ __launch_bounds__(256) void ln_kernel(
    const float* __restrict__ X, const float* __restrict__ w,
    const float* __restrict__ b, void* __restrict__ outp)
{
    int row = blockIdx.x * 4 + (threadIdx.x >> 6);
    int lane = threadIdx.x & 63;
    const float4 v = *(const float4*)(X + (size_t)row * D_ + lane * 4);
    float s = v.x + v.y + v.z + v.w;
    #pragma unroll
    for (int m = 1; m < 64; m <<= 1) s += __shfl_xor(s, m, 64);
    float mu = s * (1.0f / 256.0f);
    float dx = v.x - mu, dy = v.y - mu, dz = v.z - mu, dw = v.w - mu;
    float vs = dx * dx + dy * dy + dz * dz + dw * dw;
    #pragma unroll
    for (int m = 1; m < 64; m <<= 1) vs += __shfl_xor(vs, m, 64);
    float inv = rsqrtf(vs * (1.0f / 256.0f) + LN_EPS);
    float4 wv = *(const float4*)(w + lane * 4);
    float4 bv = *(const float4*)(b + lane * 4);
    float o0 = dx * inv * wv.x + bv.x;
    float o1 = dy * inv * wv.y + bv.y;
    float o2 = dz * inv * wv.z + bv.z;
    float o3 = dw * inv * wv.w + bv.w;
    if constexpr (MODE == 0) {
        float4 o = { o0, o1, o2, o3 };
        *(float4*)((float*)outp + (size_t)row * D_ + lane * 4) = o;
    } else {
        ushort4 o = { bf16b(o0), bf16b(o1), bf16b(o2), bf16b(o3) };
        *(ushort4*)((ushort*)outp + (size_t)row * D_ + lane * 4) = o;
    }
}

// ---------------------------------------------------------------------------
// Fused LN + head-pack + V-transpose (as R11).
// ---------------------------------------------------------------------------
__global__ __launch_bounds__(256) void lnv_kernel(
    const float* __restrict__ X, const float* __restrict__ w,
    const float* __restrict__ b, ushort* __restrict__ XNB,
    ushort* __restrict__ VTI)
{
    __shared__ ushort Ts[64][264];
    const int blk = blockIdx.x;
    const int bb = blk >> 4;                 // batch
    const int sblk = (blk & 15) * 64;        // s-block base
    const int wv = threadIdx.x >> 6, lane = threadIdx.x & 63;

    #pragma unroll
    for (int p = 0; p < 16; ++p) {
        int srow = p * 4 + wv;               // 0..63
        int row = bb * S_ + sblk + srow;
        const float4 v = *(const float4*)(X + (size_t)row * D_ + lane * 4);
        float s = v.x + v.y + v.z + v.w;
        #pragma unroll
        for (int m = 1; m < 64; m <<= 1) s += __shfl_xor(s, m, 64);
        float mu = s * (1.0f / 256.0f);
        float dx = v.x - mu, dy = v.y - mu, dz = v.z - mu, dw = v.w - mu;
        float vs = dx * dx + dy * dy + dz * dz + dw * dw;
        #pragma unroll
        for (int m = 1; m < 64; m <<= 1) vs += __shfl_xor(vs, m, 64);
        float inv = rsqrtf(vs * (1.0f / 256.0f) + LN_EPS);
        float4 wvv = *(const float4*)(w + lane * 4);
        float4 bvv = *(const float4*)(b + lane * 4);
        ushort4 o = { bf16b(dx * inv * wvv.x + bvv.x),
                      bf16b(dy * inv * wvv.y + bvv.y),
                      bf16b(dz * inv * wvv.z + bvv.z),
                      bf16b(dw * inv * wvv.w + bvv.w) };
        int h = lane >> 3, dd = (lane & 7) * 4;
        *(ushort4*)(XNB + (((size_t)(bb * H_ + h) * S_ + sblk + srow) * HD_ + dd)) = o;
        *(ushort4*)&Ts[srow][lane * 4] = o;
    }
    __syncthreads();

    const int h = threadIdx.x >> 5, d = threadIdx.x & 31;
    const int hd = threadIdx.x;              // column in Ts
    ushort* dst = VTI + ((size_t)(bb * H_ + h) * HD_ + d) * S_ + sblk;
    #pragma unroll
    for (int c8 = 0; c8 < 8; ++c8) {
        uint4 o;
        uint tmp[4];
        #pragma unroll
        for (int pair = 0; pair < 4; ++pair) {
            int c0 = c8 * 8 + pair * 2;
            int c1 = c0 + 1;
            int t0 = 16 * (((c0 >> 5) & 1) + 2 * ((c0 >> 2) & 1)) + 4 * ((c0 >> 3) & 3) + (c0 & 3);
            int t1 = 16 * (((c1 >> 5) & 1) + 2 * ((c1 >> 2) & 1)) + 4 * ((c1 >> 3) & 3) + (c1 & 3);
            tmp[pair] = (uint)Ts[t0][hd] | ((uint)Ts[t1][hd] << 16);
        }
        o.x = tmp[0]; o.y = tmp[1]; o.z = tmp[2]; o.w = tmp[3];
        *(uint4*)(dst + c8 * 8) = o;
    }
}

// ---------------------------------------------------------------------------
// Flash attention v7 + setprio (T5) around MFMA clusters.
// 128-key rounds, cheap EXACTR, double-buffered LDS via global_load_lds.
// ---------------------------------------------------------------------------
__global__ __launch_bounds__(256) void attn_kernel(
    const ushort* __restrict__ XNB, const ushort* __restrict__ VTI,
    float* __restrict__ X)
{
    __shared__ ushort Kl[2][4096];
    __shared__ ushort Vl[2][4096];

    const int bi = blockIdx.x;
    const int xcd = bi & 7, m = bi >> 3;          // m in [0,128)
    const int bh = xcd * 16 + (m >> 3);           // 16 bh per XCD
    const int bx = m & 7;                         // q-block (of 128) within bh
    const int b = bh >> 3, h = bh & 7;

    const ushort* __restrict__ base = XNB + (size_t)bh * (S_ * HD_);
    const ushort* __restrict__ vbase = VTI + (size_t)bh * (HD_ * S_);
    const int tid = threadIdx.x;
    const int w = tid >> 6, l = tid & 63, g = l >> 4, ll = l & 15;
    const int q0 = bx * 128 + w * 32;
    const int qgA = q0 + ll, qgB = q0 + 16 + ll;
    const int xq = q0 >> 5;
    const float C1 = SCALE_ * LOG2E_;

    frag qfA = *(const frag*)(base + (size_t)qgA * HD_ + g * 8);
    frag qfB = *(const frag*)(base + (size_t)qgB * HD_ + g * 8);
    #pragma unroll
    for (int i = 0; i < 8; ++i) {
        float fa = __builtin_bit_cast(float, ((uint)(ushort)qfA[i]) << 16);
        float fb = __builtin_bit_cast(float, ((uint)(ushort)qfB[i]) << 16);
        qfA[i] = (short)bf16b(fa * C1);
        qfB[i] = (short)bf16b(fb * C1);
    }

    const float slr = -exp2f(-(0.5f + (float)h)) * LOG2E_;
    const float sll = -exp2f(-(1.0f + (float)h)) * LOG2E_;
    const int itb = 2 * bx + (w >> 1);

    float dabs[4], d16m[4], d16p[4];
    #pragma unroll
    for (int r = 0; r < 4; ++r) {
        int del = ll - 4 * g - r;
        dabs[r] = (float)abs(del);
        d16m[r] = (float)(16 - del);
        d16p[r] = (float)(16 + del);
    }

    f32x4 o0A = {0,0,0,0}, o1A = {0,0,0,0}, osA = {0,0,0,0};
    f32x4 o0B = {0,0,0,0}, o1B = {0,0,0,0}, osB = {0,0,0,0};
    const f32x4 zc = {0,0,0,0};
    const short one_s = (short)0x3F80;
    const frag ones = { one_s, one_s, one_s, one_s, one_s, one_s, one_s, one_s };

    const ushort* ksrc = base  + (size_t)(16 * w + ll) * HD_ + g * 8;
    const ushort* vsrc = vbase + (size_t)((w >> 1) * 16 + ll) * S_ + (w & 1) * 32 + g * 8;
    const int dst = (w * 64 + l) * 8;

#define STAGE(NB, T2)                                                         \
    gload16(ksrc + (size_t)(T2) * 128 * HD_,            &Kl[NB][dst]);        \
    gload16(ksrc + (size_t)(T2) * 128 * HD_ + 64 * HD_, &Kl[NB][dst + 2048]); \
    gload16(vsrc + (T2) * 128,                          &Vl[NB][dst]);        \
    gload16(vsrc + (T2) * 128 + 64,                     &Vl[NB][dst + 2048]);

    STAGE(0, 0)
    __syncthreads();

#define EXACTR(r)                                                             \
  { int t0 = tb + 4 * g + (r);                                                \
    float sA0 = (t0      > qgA) ? slr : sll;                                  \
    float sA1 = (t0 + 16 > qgA) ? slr : sll;                                  \
    float sA2 = (t0 + 32 > qgA) ? slr : sll;                                  \
    float sA3 = (t0 + 48 > qgA) ? slr : sll;                                  \
    float sB0 = (t0      > qgB) ? slr : sll;                                  \
    float sB1 = (t0 + 16 > qgB) ? slr : sll;                                  \
    float sB2 = (t0 + 32 > qgB) ? slr : sll;                                  \
    float sB3 = (t0 + 48 > qgB) ? slr : sll;                                  \
    eA0[r] = exp2_raw(fmaf(sA0, dabs[r] + ax0, sa0[r]));                      \
    eA1[r] = exp2_raw(fmaf(sA1, d16m[r] + ax0, sa1[r]));                      \
    eA2[r] = exp2_raw(fmaf(sA2, dabs[r] + ax1, sa2[r]));                      \
    eA3[r] = exp2_raw(fmaf(sA3, d16m[r] + ax1, sa3[r]));                      \
    eB0[r] = exp2_raw(fmaf(sB0, d16p[r] + ax0, sb0[r]));                      \
    eB1[r] = exp2_raw(fmaf(sB1, dabs[r] + ax0, sb1[r]));                      \
    eB2[r] = exp2_raw(fmaf(sB2, d16p[r] + ax1, sb2[r]));                      \
    eB3[r] = exp2_raw(fmaf(sB3, dabs[r] + ax1, sb3[r])); }

#define FASTR(r)                                                              \
    eA0[r] = exp2_raw(fmaf(sl, dabs[r] + ax0, sa0[r]));                       \
    eA1[r] = exp2_raw(fmaf(sl, d16m[r] + ax0, sa1[r]));                       \
    eA2[r] = exp2_raw(fmaf(sl, dabs[r] + ax1, sa2[r]));                       \
    eA3[r] = exp2_raw(fmaf(sl, d16m[r] + ax1, sa3[r]));                       \
    eB0[r] = exp2_raw(fmaf(sl, d16p[r] + ax0, sb0[r]));                       \
    eB1[r] = exp2_raw(fmaf(sl, dabs[r] + ax0, sb1[r]));                       \
    eB2[r] = exp2_raw(fmaf(sl, d16p[r] + ax1, sb2[r]));                       \
    eB3[r] = exp2_raw(fmaf(sl, dabs[r] + ax1, sb3[r]));

#define HALF(IT, OFF)                                                         \
  { const int tb = (IT) * 64;                                                 \
    frag K0 = *(const frag*)&Kl[cur][(OFF) + l * 8];                          \
    frag K1 = *(const frag*)&Kl[cur][(OFF) + 512 + l * 8];                    \
    frag K2 = *(const frag*)&Kl[cur][(OFF) + 1024 + l * 8];                   \
    frag K3 = *(const frag*)&Kl[cur][(OFF) + 1536 + l * 8];                   \
    frag V0 = *(const frag*)&Vl[cur][(OFF) + l * 8];                          \
    frag V2 = *(const frag*)&Vl[cur][(OFF) + 512 + l * 8];                    \
    frag V1 = *(const frag*)&Vl[cur][(OFF) + 1024 + l * 8];                   \
    frag V3 = *(const frag*)&Vl[cur][(OFF) + 1536 + l * 8];                   \
    __builtin_amdgcn_s_setprio(1);                                            \
    f32x4 sa0 = MFMA(K0, qfA, zc);                                            \
    f32x4 sa1 = MFMA(K1, qfA, zc);                                            \
    f32x4 sa2 = MFMA(K2, qfA, zc);                                            \
    f32x4 sa3 = MFMA(K3, qfA, zc);                                            \
    f32x4 sb0 = MFMA(K0, qfB, zc);                                            \
    f32x4 sb1 = MFMA(K1, qfB, zc);                                            \
    f32x4 sb2 = MFMA(K2, qfB, zc);                                            \
    f32x4 sb3 = MFMA(K3, qfB, zc);                                            \
    __builtin_amdgcn_s_setprio(0);                                            \
    const float ax0 = (float)abs(xq - 2 * (IT));                              \
    const float ax1 = (float)abs(xq - 2 * (IT) - 1);                          \
    f32x4 eA0, eA1, eA2, eA3, eB0, eB1, eB2, eB3;                             \
    if ((IT) == itb) {                                                        \
        EXACTR(0) EXACTR(1) EXACTR(2) EXACTR(3)                               \
    } else {                                                                  \
        const float sl = ((IT) > itb) ? slr : sll;                            \
        FASTR(0) FASTR(1) FASTR(2) FASTR(3)                                   \
    }                                                                         \
    uint4 pa0 = { cvt_pk_bf16(eA0[0], eA0[1]), cvt_pk_bf16(eA0[2], eA0[3]),   \
                  cvt_pk_bf16(eA2[0], eA2[1]), cvt_pk_bf16(eA2[2], eA2[3]) }; \
    uint4 pa1 = { cvt_pk_bf16(eA1[0], eA1[1]), cvt_pk_bf16(eA1[2], eA1[3]),   \
                  cvt_pk_bf16(eA3[0], eA3[1]), cvt_pk_bf16(eA3[2], eA3[3]) }; \
    uint4 pb0 = { cvt_pk_bf16(eB0[0], eB0[1]), cvt_pk_bf16(eB0[2], eB0[3]),   \
                  cvt_pk_bf16(eB2[0], eB2[1]), cvt_pk_bf16(eB2[2], eB2[3]) }; \
    uint4 pb1 = { cvt_pk_bf16(eB1[0], eB1[1]), cvt_pk_bf16(eB1[2], eB1[3]),   \
                  cvt_pk_bf16(eB3[0], eB3[1]), cvt_pk_bf16(eB3[2], eB3[3]) }; \
    frag pfA0 = __builtin_bit_cast(frag, pa0);                                \
    frag pfA1 = __builtin_bit_cast(frag, pa1);                                \
    frag pfB0 = __builtin_bit_cast(frag, pb0);                                \
    frag pfB1 = __builtin_bit_cast(frag, pb1);                                \
    __builtin_amdgcn_s_setprio(1);                                            \
    o0A = MFMA(pfA0, V0, o0A);  o1A = MFMA(pfA0, V1, o1A);                    \
    osA = MFMA(pfA0, ones, osA);                                              \
    o0A = MFMA(pfA1, V2, o0A);  o1A = MFMA(pfA1, V3, o1A);                    \
    osA = MFMA(pfA1, ones, osA);                                              \
    o0B = MFMA(pfB0, V0, o0B);  o1B = MFMA(pfB0, V1, o1B);                    \
    osB = MFMA(pfB0, ones, osB);                                              \
    o0B = MFMA(pfB1, V2, o0B);  o1B = MFMA(pfB1, V3, o1B);                    \
    osB = MFMA(pfB1, ones, osB);                                              \
    __builtin_amdgcn_s_setprio(0); }

    for (int rt = 0; rt < 8; ++rt) {
        const int cur = rt & 1, nxt = cur ^ 1;
        STAGE(nxt, (rt + 1) & 7)
        HALF(2 * rt, 0)
        HALF(2 * rt + 1, 2048)
        __syncthreads();
    }
#undef HALF
#undef FASTR
#undef EXACTR
#undef STAGE

    #pragma unroll
    for (int r = 0; r < 4; ++r) {
        float invA = 1.0f / osA[r];
        float invB = 1.0f / osB[r];
        float* xpA = X + ((size_t)(b * S_ + q0 + g * 4 + r)) * D_ + h * HD_;
        float* xpB = X + ((size_t)(b * S_ + q0 + 16 + g * 4 + r)) * D_ + h * HD_;
        xpA[ll]      += o0A[r] * invA;
        xpA[16 + ll] += o1A[r] * invA;
        xpB[ll]      += o0B[r] * invB;
        xpB[16 + ll] += o1B[r] * invB;
    }
}

// ---------------------------------------------------------------------------
// GEMM1: H = GELU(A @ W1^T + b1). BK=64 (R14 best). 1D grid 1024, XCD-remapped.
// ---------------------------------------------------------------------------
__global__ __launch_bounds__(256) void gemm1_kernel(
    const ushort* __restrict__ A, const ushort* __restrict__ Bt,
    const float* __restrict__ bias, ushort* __restrict__ Hout)
{
    __shared__ ushort As[2 * 4096];   // [ks][128][32]
    __shared__ ushort Bs[2 * 4096];
    const int bid = blockIdx.x;
    const int xcd = bid & 7, i = bid >> 3;        // i in [0,128)
    const int row0 = (xcd * 16 + (i >> 3)) * 128;
    const int col0 = (i & 7) * 128;
    const int tid = threadIdx.x;
    const int w = tid >> 6, l = tid & 63, g = l >> 4, ll = l & 15;
    const int wm = w >> 1, wn = w & 1;

    const int srow = w * 32 + (l >> 2);
    const int scol = (l & 3) * 8;
    const ushort* ga = A  + (size_t)(row0 + srow) * 256 + scol;
    const ushort* gb = Bt + (size_t)(col0 + srow) * 256 + scol;
    const int dst = w * 1024 + l * 8;

    f32x4 acc[4][4] = {};
    for (int k0 = 0; k0 < 256; k0 += 64) {
        __syncthreads();
        #pragma unroll
        for (int sub = 0; sub < 2; ++sub) {
            gload16(ga + k0 + sub * 32,            &As[sub * 4096 + dst]);
            gload16(ga + k0 + sub * 32 + 16 * 256, &As[sub * 4096 + dst + 512]);
            gload16(gb + k0 + sub * 32,            &Bs[sub * 4096 + dst]);
            gload16(gb + k0 + sub * 32 + 16 * 256, &Bs[sub * 4096 + dst + 512]);
        }
        __syncthreads();
        #pragma unroll
        for (int sub = 0; sub < 2; ++sub) {
            frag af[4], bfr[4];
            #pragma unroll
            for (int mb = 0; mb < 4; ++mb)
                af[mb] = *(const frag*)&As[sub * 4096 + (wm * 64 + mb * 16 + ll) * 32 + g * 8];
            #pragma unroll
            for (int nb = 0; nb < 4; ++nb)
                bfr[nb] = *(const frag*)&Bs[sub * 4096 + (wn * 64 + nb * 16 + ll) * 32 + g * 8];
            #pragma unroll
            for (int mb = 0; mb < 4; ++mb)
                #pragma unroll
                for (int nb = 0; nb < 4; ++nb)
                    acc[mb][nb] = MFMA(af[mb], bfr[nb], acc[mb][nb]);
        }
    }

    #pragma unroll
    for (int nb = 0; nb < 4; ++nb) {
        int col = col0 + wn * 64 + nb * 16 + ll;
        float bv = bias[col];
        #pragma unroll
        for (int mb = 0; mb < 4; ++mb) {
            #pragma unroll
            for (int r = 0; r < 4; ++r) {
                int row = row0 + wm * 64 + mb * 16 + g * 4 + r;
                float v = acc[mb][nb][r] + bv;
                float u2 = 1.5957691216f * v + 0.0713548162f * (v * v * v);
                float e = exp2_raw(u2 * LOG2E_);
                float rr = __builtin_amdgcn_rcpf(e + 1.0f);
                float gl = v - v * rr;
                Hout[(size_t)row * 1024 + col] = bf16b(gl);
            }
        }
    }
}

// ---------------------------------------------------------------------------
// GEMM2: X += A @ W2^T + b2. BK=64 (R14 best). 1D grid 512, XCD-remapped.
// ---------------------------------------------------------------------------
__global__ __launch_bounds__(256) void gemm2_kernel(
    const ushort* __restrict__ A, const ushort* __restrict__ Bt,
    const float* __restrict__ bias, float* __restrict__ X)
{
    __shared__ ushort As[2 * 4096];   // [ks][128][32]
    __shared__ ushort Bs[2 * 2048];   // [ks][64][32]
    const int bid = blockIdx.x;
    const int xcd = bid & 7, i = bid >> 3;        // i in [0,64)
    const int row0 = (xcd * 16 + (i >> 2)) * 128;
    const int col0 = (i & 3) * 64;
    const int tid = threadIdx.x;
    const int w = tid >> 6, l = tid & 63, g = l >> 4, ll = l & 15;

    const int srow = w * 32 + (l >> 2);
    const int scol = (l & 3) * 8;
    const ushort* ga = A  + (size_t)(row0 + srow) * 1024 + scol;
    const ushort* gb = Bt + (size_t)(col0 + w * 16 + (l >> 2)) * 1024 + scol;
    const int dstA = w * 1024 + l * 8;
    const int dstB = w * 512 + l * 8;

    f32x4 acc[2][4] = {};
    for (int k0 = 0; k0 < 1024; k0 += 64) {
        __syncthreads();
        #pragma unroll
        for (int sub = 0; sub < 2; ++sub) {
            gload16(ga + k0 + sub * 32,             &As[sub * 4096 + dstA]);
            gload16(ga + k0 + sub * 32 + 16 * 1024, &As[sub * 4096 + dstA + 512]);
            gload16(gb + k0 + sub * 32,             &Bs[sub * 2048 + dstB]);
        }
        __syncthreads();
        #pragma unroll
        for (int sub = 0; sub < 2; ++sub) {
            frag af[2], bfr[4];
            #pragma unroll
            for (int mb = 0; mb < 2; ++mb)
                af[mb] = *(const frag*)&As[sub * 4096 + (w * 32 + mb * 16 + ll) * 32 + g * 8];
            #pragma unroll
            for (int nb = 0; nb < 4; ++nb)
                bfr[nb] = *(const frag*)&Bs[sub * 2048 + (nb * 16 + ll) * 32 + g * 8];
            #pragma unroll
            for (int mb = 0; mb < 2; ++mb)
                #pragma unroll
                for (int nb = 0; nb < 4; ++nb)
                    acc[mb][nb] = MFMA(af[mb], bfr[nb], acc[mb][nb]);
        }
    }

    #pragma unroll
    for (int nb = 0; nb < 4; ++nb) {
        int col = col0 + nb * 16 + ll;
        float bv = bias[col];
        #pragma unroll
        for (int mb = 0; mb < 2; ++mb) {
            #pragma unroll
            for (int r = 0; r < 4; ++r) {
                int row = row0 + w * 32 + mb * 16 + g * 4 + r;
                float* xp = X + (size_t)row * 256 + col;
                *xp += acc[mb][nb][r] + bv;
            }
        }
    }
}

// ---------------------------------------------------------------------------
extern "C" void kernel_launch(void* const* d_in, const int* in_sizes, int n_in,
                              void* d_out, int out_size, void* d_ws, size_t ws_size,
                              hipStream_t stream)
{
    const int*   tokens  = (const int*)d_in[0];
    const int*   pos_ids = (const int*)d_in[1];
    const float* emb     = (const float*)d_in[2];
    const float* iw      = (const float*)d_in[3];
    const float* pw      = (const float*)d_in[4];
    const float* ln1w    = (const float*)d_in[5];
    const float* ln1b    = (const float*)d_in[6];
    const float* ln2w    = (const float*)d_in[7];
    const float* ln2b    = (const float*)d_in[8];
    const float* w1      = (const float*)d_in[9];
    const float* b1      = (const float*)d_in[10];
    const float* w2      = (const float*)d_in[11];
    const float* b2      = (const float*)d_in[12];
    const float* lnfw    = (const float*)d_in[13];
    const float* lnfb    = (const float*)d_in[14];

    float* x = (float*)d_out;                    // [B,S,D] f32 residual stream
    char* ws = (char*)d_ws;
    ushort* xn   = (ushort*)ws;                  // 8,388,608 B
    ushort* vti  = (ushort*)(ws + 8388608);      // 8,388,608 B
    ushort* hbuf = (ushort*)(ws + 16777216);     // 33,554,432 B
    ushort* w1t  = (ushort*)(ws + 50331648);     // 3,145,728 B  [L][1024][256]
    ushort* w2t  = (ushort*)(ws + 53477376);     // 3,145,728 B  [L][256][1024]

    wtr_kernel<<<dim3(32, 8, L_), 256, 0, stream>>>(w1, w1t, 256, 1024);
    wtr_kernel<<<dim3(8, 32, L_), 256, 0, stream>>>(w2, w2t, 1024, 256);

    embed_kernel<<<B_ * S_, 256, 0, stream>>>(tokens, pos_ids, emb, iw, pw, x);

    for (int l = 0; l < L_; l++) {
        lnv_kernel<<<(B_ * S_) / 64, 256, 0, stream>>>(
            x, ln1w + l * D_, ln1b + l * D_, xn, vti);
        attn_kernel<<<(S_ / 128) * B_ * H_, 256, 0, stream>>>(xn, vti, x);
        ln_kernel<2><<<(B_ * S_) / 4, 256, 0, stream>>>(x, ln2w + l * D_, ln2b + l * D_, xn);
        gemm1_kernel<<<1024, 256, 0, stream>>>(
            xn, w1t + (size_t)l * D_ * H2_, b1 + (size_t)l * H2_, hbuf);
        gemm2_kernel<<<512, 256, 0, stream>>>(
            hbuf, w2t + (size_t)l * H2_ * D_, b2 + (size_t)l * D_, x);
    }
    ln_kernel<0><<<(B_ * S_) / 4, 256, 0, stream>>>(x, lnfw, lnfb, x);
}